// Round 15
// baseline (483.635 us; speedup 1.0000x reference)
//
#include <hip/hip_runtime.h>
#include <hip/hip_bf16.h>

typedef float BF;
__device__ __forceinline__ float ldf(const BF* p, int i) { return p[i]; }

typedef _Float16 h8 __attribute__((ext_vector_type(8)));
typedef float f4 __attribute__((ext_vector_type(4)));

static constexpr int N_NODES = 20000;
static constexpr int N_EDGES = 50000;
static constexpr int E_PAD   = 50176;  // 392*128
static constexpr int N_MSGB  = 392;    // 128-edge tiles (x-dim; y=2 o-halves)
static constexpr int N_PAD   = 20032;  // 313*64
static constexpr int BROW    = 136;    // k_gru LDS row
static constexpr int SROW    = 72;     // k_msg s-tile row (64+8 halves, 16B-aligned)
static constexpr int N_B     = 79;     // ceil(20000/256)
static constexpr int MAXSEG  = 2048;

__device__ __forceinline__ float sigf(float x) { return 1.f / (1.f + __expf(-x)); }
__device__ __forceinline__ float tanh_f(float x) {
  float e = __expf(2.f * x);
  return 1.f - 2.f / (e + 1.f);
}

// ================= prep1 =================
static constexpr int S1_LIN0 = 5000;   // 4 nodes/block
static constexpr int S1_QS   = 2048;   // o-half-major frag swizzle
static constexpr int S1_WCAT = 128;
static constexpr int S1_B2S  = 16;     // 8 frags * 512 / 256
static constexpr int S1_DEG  = 196;
static constexpr int PREP1_BLOCKS = S1_LIN0 + S1_QS + S1_WCAT + S1_B2S + 1 + 1 + S1_DEG;

__global__ void k_prep1(const BF* __restrict__ x, const int* __restrict__ batch,
                        const int* __restrict__ dst,
                        const BF* __restrict__ w0, const BF* __restrict__ b0,
                        const BF* __restrict__ w2, const BF* __restrict__ b2,
                        const BF* __restrict__ gwih, const BF* __restrict__ gwhh,
                        const BF* __restrict__ gbih, const BF* __restrict__ gbhh,
                        float* __restrict__ h, _Float16* __restrict__ h16,
                        _Float16* __restrict__ Qs, _Float16* __restrict__ Wcat,
                        float* __restrict__ bcat, _Float16* __restrict__ b2s,
                        int* __restrict__ seg, int* __restrict__ degi,
                        int* __restrict__ bsum) {
  int bid = blockIdx.x, t = threadIdx.x;
  if (bid < S1_LIN0) {                      // lin0, x staged in LDS (read once)
    __shared__ float xs[64];
    if (t < 64) xs[t] = ldf(x, bid * 64 + t);
    __syncthreads();
    int nl = t >> 6, o = t & 63;
    float acc = ldf(b0, o);
#pragma unroll
    for (int f = 0; f < 16; ++f) acc += xs[nl * 16 + f] * ldf(w0, o * 16 + f);
    float v = fmaxf(acc, 0.f);
    int idx = bid * 256 + t;
    h[idx] = v;
    h16[idx] = (_Float16)v;
    return;
  }
  bid -= S1_LIN0;
  if (bid < S1_QS) {                        // Qs o-half-major: [oh][dl][f8=tk*2+ctl][ln][8]
    int i = bid * 256 + t;
    int j = i & 7, ln = (i >> 3) & 63, f8 = (i >> 9) & 7;
    int dl = (i >> 12) & 63, oh = i >> 18;
    int tk = f8 >> 1, ctl = f8 & 1;
    int o = oh * 32 + ctl * 16 + (ln & 15);
    int k = tk * 32 + (ln >> 4) * 8 + j;
    Qs[i] = (_Float16)ldf(w2, (dl * 64 + o) * 128 + k);
    return;
  }
  bid -= S1_QS;
  if (bid < S1_WCAT) {                      // GRU weight pack
    int idx = bid * 256 + t, row = idx >> 7, k = idx & 127;
    int g = row >> 6, rr = row & 63;
    float v = 0.f;
    if (g == 0) v = (k < 64) ? ldf(gwih, rr * 64 + k) : ldf(gwhh, rr * 64 + (k - 64));
    else if (g == 1) v = (k < 64) ? ldf(gwih, (64 + rr) * 64 + k) : ldf(gwhh, (64 + rr) * 64 + (k - 64));
    else if (g == 2) v = (k < 64) ? ldf(gwih, (128 + rr) * 64 + k) : 0.f;
    else v = (k < 64) ? 0.f : ldf(gwhh, (128 + rr) * 64 + (k - 64));
    Wcat[idx] = (_Float16)v;
    return;
  }
  bid -= S1_WCAT;
  if (bid < S1_B2S) {                       // b2s frag-major (f&3 = o-quarter, f>>2 = tp)
    int idx = bid * 256 + t;                // 8 frags * 512
    int f = idx >> 9, ln = (idx >> 3) & 63, j = idx & 7;
    int o = (f & 3) * 16 + (ln & 15);
    int d = (f >> 2) * 32 + (ln >> 4) * 8 + j;
    b2s[idx] = (_Float16)ldf(b2, d * 64 + o);
    return;
  }
  bid -= S1_B2S;
  if (bid == 0) {                           // bcat
    float v;
    if (t < 128) v = ldf(gbih, t) + ldf(gbhh, t);
    else if (t < 192) v = ldf(gbih, t);
    else v = ldf(gbhh, t - 64);
    bcat[t] = v;
    return;
  }
  bid -= 1;
  if (bid == 0) {                           // seg starts (batch sorted)
    if (t > 128) return;
    if (t == 128) { seg[128] = N_NODES; return; }
    int lo = 0, hi = N_NODES;
    while (lo < hi) {
      int mid = (lo + hi) >> 1;
      if (batch[mid] < t) lo = mid + 1; else hi = mid;
    }
    seg[t] = lo;
    return;
  }
  bid -= 1;
  {                                         // degree counts + per-scanblock sums
    int e = bid * 256 + t;
    if (e < N_EDGES) {
      int d = dst[e];
      atomicAdd(&degi[d], 1);
      atomicAdd(&bsum[d >> 8], 1);
    }
  }
}

// ================= parallel scan -> CSR edge permutation =================
__global__ void k_scanA(const int* __restrict__ bsum, int* __restrict__ boff) {
  __shared__ int sd[128];
  int t = threadIdx.x;
  int x = (t < N_B) ? bsum[t] : 0;
  sd[t] = x;
  __syncthreads();
#pragma unroll
  for (int o = 1; o < 128; o <<= 1) {
    int val = (t >= o) ? sd[t - o] : 0;
    __syncthreads();
    sd[t] += val;
    __syncthreads();
  }
  if (t < N_B) boff[t] = sd[t] - x;
}

__global__ void k_scanB(const int* __restrict__ degi, const int* __restrict__ boff,
                        int* __restrict__ cursor) {
  __shared__ int sd[256];
  int b = blockIdx.x, t = threadIdx.x;
  int v = b * 256 + t;
  int x = (v < N_NODES) ? degi[v] : 0;
  sd[t] = x;
  __syncthreads();
#pragma unroll
  for (int o = 1; o < 256; o <<= 1) {
    int val = (t >= o) ? sd[t - o] : 0;
    __syncthreads();
    sd[t] += val;
    __syncthreads();
  }
  if (v < N_NODES) cursor[v] = boff[b] + sd[t] - x;
}

__global__ void k_fill(const int* __restrict__ dst, int* __restrict__ cursor,
                       int* __restrict__ eperm) {
  int e = blockIdx.x * 256 + threadIdx.x;
  if (e < N_EDGES) {
    int pos = atomicAdd(&cursor[dst[e]], 1);
    eperm[pos] = e;
  }
}

// ================= prep2: permuted edge MLP (8 edges/block) + src/dst =================
static constexpr int S2_MLP = E_PAD / 8;   // 6272 blocks, 8 edges x 128 j
static constexpr int S2_SP  = 196;

__global__ void k_prep2(const BF* __restrict__ ea, const int* __restrict__ src,
                        const int* __restrict__ dst, const int* __restrict__ eperm,
                        const BF* __restrict__ w1, const BF* __restrict__ b1,
                        _Float16* __restrict__ hidf, int* __restrict__ spadp,
                        int* __restrict__ dpadp) {
  int bid = blockIdx.x, t = threadIdx.x;
  if (bid < S2_MLP) {
    __shared__ float eas[40];
    __shared__ int el8[8];
    if (t < 8) { int pos = bid * 8 + t; el8[t] = (pos < N_EDGES) ? eperm[pos] : -1; }
    __syncthreads();
    if (t < 40) { int e = el8[t / 5]; eas[t] = (e >= 0) ? ldf(ea, e * 5 + (t % 5)) : 0.f; }
    __syncthreads();
#pragma unroll
    for (int rep = 0; rep < 4; ++rep) {
      int item = t + rep * 256;
      int le = item >> 7, j = item & 127;
      int pos = bid * 8 + le;
      float v = 0.f;
      if (pos < N_EDGES) {
        float acc = ldf(b1, j);
#pragma unroll
        for (int i = 0; i < 5; ++i) acc += eas[le * 5 + i] * ldf(w1, j * 5 + i);
        v = fmaxf(acc, 0.f);
      }
      hidf[(size_t)pos * 128 + j] = (_Float16)v;
    }
    return;
  }
  bid -= S2_MLP;
  {
    int pos = bid * 256 + t;
    if (pos < E_PAD) {
      int e = (pos < N_EDGES) ? eperm[pos] : -1;
      spadp[pos] = (e >= 0) ? src[e] : 0;
      dpadp[pos] = (e >= 0) ? dst[e] : 0;
    }
  }
}

// ================= NNConv message kernel v14 =================
// r14 structure + dl x2 per barrier stage (32 stages, 32 MFMA/barrier) and
// batched s-reads (1 ds_read_b128 per mt per 4 stages). LDS 50 KB -> 3/CU.
__launch_bounds__(256, 3)
__global__ void k_msg(const _Float16* __restrict__ h16, const _Float16* __restrict__ hidf,
                      const _Float16* __restrict__ Qs, const _Float16* __restrict__ b2s,
                      const int* __restrict__ spadp, const int* __restrict__ dpadp,
                      float* __restrict__ agg) {
  __shared__ _Float16 s_lds[128 * SROW];   // 18 KB
  __shared__ _Float16 b_lds[2][8192];      // 2 x 16 KB (dl-pair tiles)
  const int tid = threadIdx.x;
  const int wv = tid >> 6, ln = tid & 63;
  const int m0 = ln & 15, quad = ln >> 4;
  const int tb = blockIdx.x * 128;
  const int oh = blockIdx.y;

  // stage s: 2 thr/edge, 32 halves each
  {
    int el = tid >> 1, half = (tid & 1) * 32;
    int sp_ = spadp[tb + el];
    const uint4* hp4 = (const uint4*)(h16 + (size_t)sp_ * 64 + half);
#pragma unroll
    for (int c = 0; c < 4; ++c) *(uint4*)&s_lds[el * SROW + half + c * 8] = hp4[c];
  }
  // hid fragments: 2 m-tiles x 4 k-chunks (full K=128)
  h8 hvv[2][4];
#pragma unroll
  for (int mt = 0; mt < 2; ++mt) {
    int e = tb + wv * 32 + mt * 16 + m0;
    const _Float16* hp = hidf + (size_t)e * 128 + quad * 8;
#pragma unroll
    for (int c = 0; c < 4; ++c) hvv[mt][c] = *(const h8*)(hp + c * 32);
  }
  // prefetch stage 0 (dl pair 0,1 = 16 KB contiguous)
  uint4 breg[4];
  {
    const uint4* qb = (const uint4*)(Qs + (size_t)(oh * 64) * 4096);
#pragma unroll
    for (int c = 0; c < 4; ++c) breg[c] = qb[tid + c * 256];
#pragma unroll
    for (int c = 0; c < 4; ++c) *(uint4*)&b_lds[0][(tid + c * 256) * 8] = breg[c];
  }
  __syncthreads();

  f4 acc[2][2];
#pragma unroll
  for (int mt = 0; mt < 2; ++mt)
#pragma unroll
    for (int ct = 0; ct < 2; ++ct)
#pragma unroll
      for (int j = 0; j < 4; ++j) acc[mt][ct][j] = 0.f;

  h8 sv8[2];
  for (int dp = 0; dp < 32; ++dp) {
    int cur = dp & 1;
    if (dp < 31) {
      const uint4* qb = (const uint4*)(Qs + (size_t)(oh * 64 + (dp + 1) * 2) * 4096);
#pragma unroll
      for (int c = 0; c < 4; ++c) breg[c] = qb[tid + c * 256];
    }
    if ((dp & 3) == 0) {   // batch s for 8 dls (4 stages)
#pragma unroll
      for (int mt = 0; mt < 2; ++mt)
        sv8[mt] = *(const h8*)&s_lds[(wv * 32 + mt * 16 + m0) * SROW + dp * 2];
    }
#pragma unroll
    for (int il = 0; il < 2; ++il) {
      _Float16 sv0 = sv8[0][(dp & 3) * 2 + il];
      _Float16 sv1 = sv8[1][(dp & 3) * 2 + il];
      const _Float16* bb = &b_lds[cur][il * 4096];
#pragma unroll
      for (int tk = 0; tk < 4; ++tk) {
        h8 a0 = hvv[0][tk] * sv0;
        h8 a1 = hvv[1][tk] * sv1;
#pragma unroll
        for (int ctl = 0; ctl < 2; ++ctl) {
          h8 b = *(const h8*)&bb[(tk * 2 + ctl) * 512 + ln * 8];
          acc[0][ctl] = __builtin_amdgcn_mfma_f32_16x16x32_f16(a0, b, acc[0][ctl], 0, 0, 0);
          acc[1][ctl] = __builtin_amdgcn_mfma_f32_16x16x32_f16(a1, b, acc[1][ctl], 0, 0, 0);
        }
      }
    }
    if (dp < 31) {
#pragma unroll
      for (int c = 0; c < 4; ++c) *(uint4*)&b_lds[cur ^ 1][(tid + c * 256) * 8] = breg[c];
    }
    __syncthreads();
  }
  // b2 term: 2 extra K-steps, A = s rows (d-halves), B = b2 frags from L2
#pragma unroll
  for (int tp = 0; tp < 2; ++tp) {
    h8 a[2];
#pragma unroll
    for (int mt = 0; mt < 2; ++mt)
      a[mt] = *(const h8*)&s_lds[(wv * 32 + mt * 16 + m0) * SROW + tp * 32 + quad * 8];
#pragma unroll
    for (int ctl = 0; ctl < 2; ++ctl) {
      int sf = (tp << 2) | (oh * 2 + ctl);
      h8 b = *(const h8*)(b2s + sf * 512 + ln * 8);
#pragma unroll
      for (int mt = 0; mt < 2; ++mt)
        acc[mt][ctl] = __builtin_amdgcn_mfma_f32_16x16x32_f16(a[mt], b, acc[mt][ctl], 0, 0, 0);
    }
  }
  // epilogue: coalesced atomicAdd into this o-half's disjoint segment
#pragma unroll
  for (int mt = 0; mt < 2; ++mt) {
#pragma unroll
    for (int r = 0; r < 4; ++r) {
      int pos = tb + wv * 32 + mt * 16 + quad * 4 + r;
      if (pos < N_EDGES) {
        float* ap = agg + (size_t)dpadp[pos] * 64 + oh * 32 + m0;
        atomicAdd(ap, acc[mt][0][r]);
        atomicAdd(ap + 16, acc[mt][1][r]);
      }
    }
  }
}

// ================= fused m-build + GRU (r11-verified, 313 blocks) =================
__launch_bounds__(256)
__global__ void k_gru(float* __restrict__ agg, const int* __restrict__ degi,
                      const BF* __restrict__ convb, const _Float16* __restrict__ W,
                      const float* __restrict__ bcat, float* __restrict__ h,
                      _Float16* __restrict__ h16) {
  __shared__ _Float16 xa[64 * BROW];
  __shared__ _Float16 wb[256 * BROW];
  __shared__ float bsh[256];
  int tid = threadIdx.x;
  int wv = tid >> 6, ln = tid & 63, m0 = ln & 15, quad = ln >> 4;
  int rowblk = blockIdx.x * 64;
  bsh[tid] = bcat[tid];
  {
    int r = tid >> 2, c0 = (tid & 3) * 16;
    int node = rowblk + r;
    _Float16 mv[16], hv[16];
    if (node < N_NODES) {
      float inv = 1.f / (float)max(degi[node], 1);
      float* ap = agg + (size_t)node * 64 + c0;
      const float* hp = h + (size_t)node * 64 + c0;
#pragma unroll
      for (int i = 0; i < 16; i += 4) {
        float4 a = *(float4*)(ap + i);
        *(float4*)(ap + i) = make_float4(0.f, 0.f, 0.f, 0.f);
        float4 hf = *(const float4*)(hp + i);
        mv[i + 0] = (_Float16)fmaxf(a.x * inv + ldf(convb, c0 + i + 0), 0.f);
        mv[i + 1] = (_Float16)fmaxf(a.y * inv + ldf(convb, c0 + i + 1), 0.f);
        mv[i + 2] = (_Float16)fmaxf(a.z * inv + ldf(convb, c0 + i + 2), 0.f);
        mv[i + 3] = (_Float16)fmaxf(a.w * inv + ldf(convb, c0 + i + 3), 0.f);
        hv[i + 0] = (_Float16)hf.x; hv[i + 1] = (_Float16)hf.y;
        hv[i + 2] = (_Float16)hf.z; hv[i + 3] = (_Float16)hf.w;
      }
    } else {
#pragma unroll
      for (int i = 0; i < 16; ++i) { mv[i] = (_Float16)0.f; hv[i] = (_Float16)0.f; }
    }
    *(uint4*)&xa[r * BROW + c0] = *(const uint4*)&mv[0];
    *(uint4*)&xa[r * BROW + c0 + 8] = *(const uint4*)&mv[8];
    *(uint4*)&xa[r * BROW + 64 + c0] = *(const uint4*)&hv[0];
    *(uint4*)&xa[r * BROW + 64 + c0 + 8] = *(const uint4*)&hv[8];
  }
#pragma unroll
  for (int c = 0; c < 16; ++c) {
    int i = tid + c * 256, r = i >> 4, ch = i & 15;
    *(uint4*)&wb[r * BROW + ch * 8] = *(const uint4*)(W + (size_t)r * 128 + ch * 8);
  }
  __syncthreads();
  f4 acc[16];
#pragma unroll
  for (int ct = 0; ct < 16; ++ct)
#pragma unroll
    for (int j = 0; j < 4; ++j) acc[ct][j] = 0.f;
#pragma unroll
  for (int t = 0; t < 4; ++t) {
    h8 a = *(const h8*)&xa[(wv * 16 + m0) * BROW + t * 32 + quad * 8];
#pragma unroll
    for (int ct = 0; ct < 16; ++ct) {
      h8 b = *(const h8*)&wb[(ct * 16 + m0) * BROW + t * 32 + quad * 8];
      acc[ct] = __builtin_amdgcn_mfma_f32_16x16x32_f16(a, b, acc[ct], 0, 0, 0);
    }
  }
#pragma unroll
  for (int c0 = 0; c0 < 4; ++c0) {
    int o = c0 * 16 + m0;
    float br = bsh[o], bz = bsh[64 + o], bn = bsh[128 + o], bh2 = bsh[192 + o];
#pragma unroll
    for (int r = 0; r < 4; ++r) {
      int row = rowblk + wv * 16 + quad * 4 + r;
      if (row < N_NODES) {
        float rr = sigf(acc[c0][r] + br);
        float zz = sigf(acc[c0 + 4][r] + bz);
        float nn = tanh_f(acc[c0 + 8][r] + bn + rr * (acc[c0 + 12][r] + bh2));
        size_t hi = (size_t)row * 64 + o;
        float hp = h[hi];
        float hn = (1.f - zz) * nn + zz * hp;
        h[hi] = hn;
        h16[hi] = (_Float16)hn;
      }
    }
  }
}

// ================= fused Set2Set (r10-verified) =================
__launch_bounds__(1024)
__global__ void k_s2s(const float* __restrict__ h, const int* __restrict__ seg,
                      const BF* __restrict__ wih, const BF* __restrict__ whh,
                      const BF* __restrict__ bih, const BF* __restrict__ bhh,
                      float* __restrict__ outp) {
  __shared__ float xrow[128], g[256], qrow[64], hc[64], ccs[64], rr_[64];
  __shared__ float evals[MAXSEG];
  __shared__ float wred[16], wred2[16], rpart[16 * 64];
  int b = blockIdx.x, t = threadIdx.x;
  int wv = t >> 6, ln = t & 63;   // 16 waves
  if (t < 64) { hc[t] = 0.f; ccs[t] = 0.f; rr_[t] = 0.f; }
  __syncthreads();
  int start = seg[b], end = seg[b + 1];
  int cnt = end - start;
  for (int st = 0; st < 3; ++st) {
    if (t < 64) xrow[t] = hc[t];
    else if (t < 128) xrow[t] = rr_[t - 64];
    __syncthreads();
    if (t < 256) {
      float acc = ldf(bih, t) + ldf(bhh, t);
      const float4* wr4 = (const float4*)(wih + t * 128);
#pragma unroll
      for (int i = 0; i < 32; ++i) {
        float4 wv4 = wr4[i];
        acc += xrow[i * 4] * wv4.x + xrow[i * 4 + 1] * wv4.y +
               xrow[i * 4 + 2] * wv4.z + xrow[i * 4 + 3] * wv4.w;
      }
      const float4* wr2 = (const float4*)(whh + t * 64);
#pragma unroll
      for (int i = 0; i < 16; ++i) {
        float4 wv4 = wr2[i];
        acc += xrow[i * 4] * wv4.x + xrow[i * 4 + 1] * wv4.y +
               xrow[i * 4 + 2] * wv4.z + xrow[i * 4 + 3] * wv4.w;
      }
      g[t] = acc;
    }
    __syncthreads();
    if (t < 64) {
      float ig = sigf(g[t]), fg = sigf(g[64 + t]);
      float gg = tanh_f(g[128 + t]), og = sigf(g[192 + t]);
      float c = fg * ccs[t] + ig * gg;
      ccs[t] = c;
      float hn = og * tanh_f(c);
      hc[t] = hn;
      qrow[t] = hn;
    }
    __syncthreads();
    float q = qrow[ln];
    float mw = -3.4e38f;
    for (int n0 = start + wv * 2; n0 < end; n0 += 32) {
      int n1 = n0 + 1;
      float p0 = h[(size_t)n0 * 64 + ln] * q;
      float p1 = (n1 < end) ? h[(size_t)n1 * 64 + ln] * q : 0.f;
#pragma unroll
      for (int off = 32; off > 0; off >>= 1) {
        p0 += __shfl_xor(p0, off);
        p1 += __shfl_xor(p1, off);
      }
      if (ln == 0) {
        evals[n0 - start] = p0;
        mw = fmaxf(mw, p0);
        if (n1 < end) { evals[n1 - start] = p1; mw = fmaxf(mw, p1); }
      }
    }
    if (ln == 0) wred[wv] = mw;
    __syncthreads();
    float gmax = -3.4e38f;
#pragma unroll
    for (int i = 0; i < 16; ++i) gmax = fmaxf(gmax, wred[i]);
    __syncthreads();
    float psum = 0.f;
    for (int i = t; i < cnt; i += 1024) {
      float a = __expf(evals[i] - gmax);
      evals[i] = a;
      psum += a;
    }
#pragma unroll
    for (int off = 32; off > 0; off >>= 1) psum += __shfl_xor(psum, off);
    if (ln == 0) wred2[wv] = psum;
    __syncthreads();
    float tsum = 0.f;
#pragma unroll
    for (int i = 0; i < 16; ++i) tsum += wred2[i];
    float inv = 1.f / fmaxf(tsum, 1e-30f);
    float racc = 0.f;
    for (int n0 = start + wv * 2; n0 < end; n0 += 32) {
      int n1 = n0 + 1;
      float a0 = evals[n0 - start] * h[(size_t)n0 * 64 + ln];
      float a1 = (n1 < end) ? evals[n1 - start] * h[(size_t)n1 * 64 + ln] : 0.f;
      racc += a0 + a1;
    }
    rpart[wv * 64 + ln] = racc;
    __syncthreads();
    if (t < 64) {
      float s = 0.f;
#pragma unroll
      for (int i = 0; i < 16; ++i) s += rpart[i * 64 + t];
      rr_[t] = s * inv;
    }
    __syncthreads();
  }
  if (t < 128) outp[b * 128 + t] = (t < 64) ? hc[t] : rr_[t - 64];
}

// ================= launch =================
extern "C" void kernel_launch(void* const* d_in, const int* in_sizes, int n_in,
                              void* d_out, int out_size, void* d_ws, size_t ws_size,
                              hipStream_t stream) {
  const BF* x      = (const BF*)d_in[0];
  const int* ei    = (const int*)d_in[1];
  const BF* ea     = (const BF*)d_in[2];
  const int* batch = (const int*)d_in[3];
  const BF* w0     = (const BF*)d_in[4];
  const BF* b0     = (const BF*)d_in[5];
  const BF* w1     = (const BF*)d_in[6];
  const BF* b1     = (const BF*)d_in[7];
  const BF* w2     = (const BF*)d_in[8];
  const BF* b2     = (const BF*)d_in[9];
  const BF* convb  = (const BF*)d_in[10];
  const BF* gwih   = (const BF*)d_in[11];
  const BF* gwhh   = (const BF*)d_in[12];
  const BF* gbih   = (const BF*)d_in[13];
  const BF* gbhh   = (const BF*)d_in[14];
  const BF* lwih   = (const BF*)d_in[15];
  const BF* lwhh   = (const BF*)d_in[16];
  const BF* lbih   = (const BF*)d_in[17];
  const BF* lbhh   = (const BF*)d_in[18];
  const int* src = ei;
  const int* dstp = ei + N_EDGES;

  char* w = (char*)d_ws;
  size_t off_b = 0;
  auto take = [&](size_t bytes) -> void* {
    void* p = w + off_b;
    off_b = (off_b + bytes + 255) & ~(size_t)255;
    return p;
  };
  _Float16* Qs   = (_Float16*)take((size_t)4096 * 128 * 2);
  _Float16* hidf = (_Float16*)take((size_t)E_PAD * 128 * 2);
  float* h       = (float*)take((size_t)N_NODES * 64 * 4);
  _Float16* h16  = (_Float16*)take((size_t)N_NODES * 64 * 2);
  float* zr      = (float*)take((size_t)(N_NODES * 64 + N_NODES + 128) * 4);  // agg|degi|bsum
  float* agg     = zr;
  int*   degi    = (int*)(zr + N_NODES * 64);
  int*   bsum    = degi + N_NODES;
  _Float16* Wcat = (_Float16*)take((size_t)256 * 128 * 2);
  float* bcat    = (float*)take((size_t)256 * 4);
  _Float16* b2s  = (_Float16*)take((size_t)8 * 512 * 2);
  int*   seg     = (int*)take((size_t)129 * 4);
  int*   boff    = (int*)take((size_t)128 * 4);
  int*   cursor  = (int*)take((size_t)N_NODES * 4);
  int*   eperm   = (int*)take((size_t)N_EDGES * 4);
  int*   spadp   = (int*)take((size_t)E_PAD * 4);
  int*   dpadp   = (int*)take((size_t)E_PAD * 4);

  hipMemsetAsync(zr, 0, (size_t)(N_NODES * 64 + N_NODES + 128) * 4, stream);
  k_prep1<<<PREP1_BLOCKS, 256, 0, stream>>>(x, batch, dstp, w0, b0, w2, b2,
                                            gwih, gwhh, gbih, gbhh,
                                            h, h16, Qs, Wcat, bcat, b2s,
                                            seg, degi, bsum);
  k_scanA<<<1, 128, 0, stream>>>(bsum, boff);
  k_scanB<<<N_B, 256, 0, stream>>>(degi, boff, cursor);
  k_fill<<<196, 256, 0, stream>>>(dstp, cursor, eperm);
  k_prep2<<<S2_MLP + S2_SP, 256, 0, stream>>>(ea, src, dstp, eperm, w1, b1,
                                              hidf, spadp, dpadp);
  for (int it = 0; it < 3; ++it) {
    k_msg<<<dim3(N_MSGB, 2), 256, 0, stream>>>(h16, hidf, Qs, b2s, spadp, dpadp, agg);
    k_gru<<<N_PAD / 64, 256, 0, stream>>>(agg, degi, convb, Wcat, bcat, h, h16);
  }
  k_s2s<<<128, 1024, 0, stream>>>(h, seg, lwih, lwhh, lbih, lbhh, (float*)d_out);
}

// Round 16
// 419.637 us; speedup vs baseline: 1.1525x; 1.1525x over previous
//
#include <hip/hip_runtime.h>
#include <hip/hip_bf16.h>

typedef float BF;
__device__ __forceinline__ float ldf(const BF* p, int i) { return p[i]; }

typedef _Float16 h8 __attribute__((ext_vector_type(8)));
typedef float f4 __attribute__((ext_vector_type(4)));

static constexpr int N_NODES = 20000;
static constexpr int N_EDGES = 50000;
static constexpr int E_PAD   = 50176;  // 392*128
static constexpr int N_MSGB  = 392;    // 128-edge tiles (x-dim; y=2 o-halves)
static constexpr int N_GRUB  = 625;    // 32-row k_gru blocks (625*32 = 20000 exact)
static constexpr int BROW    = 136;    // k_gru LDS row
static constexpr int SROW    = 72;     // k_msg s-tile row (64+8 halves, 16B-aligned)
static constexpr int N_B     = 79;     // ceil(20000/256)
static constexpr int MAXSEG  = 2048;

__device__ __forceinline__ float sigf(float x) { return 1.f / (1.f + __expf(-x)); }
__device__ __forceinline__ float tanh_f(float x) {
  float e = __expf(2.f * x);
  return 1.f - 2.f / (e + 1.f);
}

// ================= prep1 =================
static constexpr int S1_LIN0 = 5000;   // 4 nodes/block
static constexpr int S1_QS   = 2048;   // o-half-major frag swizzle
static constexpr int S1_WCAT = 128;
static constexpr int S1_B2S  = 16;     // 8 frags * 512 / 256
static constexpr int S1_DEG  = 196;
static constexpr int PREP1_BLOCKS = S1_LIN0 + S1_QS + S1_WCAT + S1_B2S + 1 + 1 + S1_DEG;

__global__ void k_prep1(const BF* __restrict__ x, const int* __restrict__ batch,
                        const int* __restrict__ dst,
                        const BF* __restrict__ w0, const BF* __restrict__ b0,
                        const BF* __restrict__ w2, const BF* __restrict__ b2,
                        const BF* __restrict__ gwih, const BF* __restrict__ gwhh,
                        const BF* __restrict__ gbih, const BF* __restrict__ gbhh,
                        float* __restrict__ h, _Float16* __restrict__ h16,
                        _Float16* __restrict__ Qs, _Float16* __restrict__ Wcat,
                        float* __restrict__ bcat, _Float16* __restrict__ b2s,
                        int* __restrict__ seg, int* __restrict__ degi,
                        int* __restrict__ bsum) {
  int bid = blockIdx.x, t = threadIdx.x;
  if (bid < S1_LIN0) {                      // lin0, x staged in LDS (read once)
    __shared__ float xs[64];
    if (t < 64) xs[t] = ldf(x, bid * 64 + t);
    __syncthreads();
    int nl = t >> 6, o = t & 63;
    float acc = ldf(b0, o);
#pragma unroll
    for (int f = 0; f < 16; ++f) acc += xs[nl * 16 + f] * ldf(w0, o * 16 + f);
    float v = fmaxf(acc, 0.f);
    int idx = bid * 256 + t;
    h[idx] = v;
    h16[idx] = (_Float16)v;
    return;
  }
  bid -= S1_LIN0;
  if (bid < S1_QS) {                        // Qs o-half-major: [oh][dl][f8=tk*2+ctl][ln][8]
    int i = bid * 256 + t;
    int j = i & 7, ln = (i >> 3) & 63, f8 = (i >> 9) & 7;
    int dl = (i >> 12) & 63, oh = i >> 18;
    int tk = f8 >> 1, ctl = f8 & 1;
    int o = oh * 32 + ctl * 16 + (ln & 15);
    int k = tk * 32 + (ln >> 4) * 8 + j;
    Qs[i] = (_Float16)ldf(w2, (dl * 64 + o) * 128 + k);
    return;
  }
  bid -= S1_QS;
  if (bid < S1_WCAT) {                      // GRU weight pack
    int idx = bid * 256 + t, row = idx >> 7, k = idx & 127;
    int g = row >> 6, rr = row & 63;
    float v = 0.f;
    if (g == 0) v = (k < 64) ? ldf(gwih, rr * 64 + k) : ldf(gwhh, rr * 64 + (k - 64));
    else if (g == 1) v = (k < 64) ? ldf(gwih, (64 + rr) * 64 + k) : ldf(gwhh, (64 + rr) * 64 + (k - 64));
    else if (g == 2) v = (k < 64) ? ldf(gwih, (128 + rr) * 64 + k) : 0.f;
    else v = (k < 64) ? 0.f : ldf(gwhh, (128 + rr) * 64 + (k - 64));
    Wcat[idx] = (_Float16)v;
    return;
  }
  bid -= S1_WCAT;
  if (bid < S1_B2S) {                       // b2s frag-major (f&3 = o-quarter, f>>2 = tp)
    int idx = bid * 256 + t;                // 8 frags * 512
    int f = idx >> 9, ln = (idx >> 3) & 63, j = idx & 7;
    int o = (f & 3) * 16 + (ln & 15);
    int d = (f >> 2) * 32 + (ln >> 4) * 8 + j;
    b2s[idx] = (_Float16)ldf(b2, d * 64 + o);
    return;
  }
  bid -= S1_B2S;
  if (bid == 0) {                           // bcat
    float v;
    if (t < 128) v = ldf(gbih, t) + ldf(gbhh, t);
    else if (t < 192) v = ldf(gbih, t);
    else v = ldf(gbhh, t - 64);
    bcat[t] = v;
    return;
  }
  bid -= 1;
  if (bid == 0) {                           // seg starts (batch sorted)
    if (t > 128) return;
    if (t == 128) { seg[128] = N_NODES; return; }
    int lo = 0, hi = N_NODES;
    while (lo < hi) {
      int mid = (lo + hi) >> 1;
      if (batch[mid] < t) lo = mid + 1; else hi = mid;
    }
    seg[t] = lo;
    return;
  }
  bid -= 1;
  {                                         // degree counts + per-scanblock sums
    int e = bid * 256 + t;
    if (e < N_EDGES) {
      int d = dst[e];
      atomicAdd(&degi[d], 1);
      atomicAdd(&bsum[d >> 8], 1);
    }
  }
}

// ================= parallel scan -> CSR edge permutation =================
__global__ void k_scanA(const int* __restrict__ bsum, int* __restrict__ boff) {
  __shared__ int sd[128];
  int t = threadIdx.x;
  int x = (t < N_B) ? bsum[t] : 0;
  sd[t] = x;
  __syncthreads();
#pragma unroll
  for (int o = 1; o < 128; o <<= 1) {
    int val = (t >= o) ? sd[t - o] : 0;
    __syncthreads();
    sd[t] += val;
    __syncthreads();
  }
  if (t < N_B) boff[t] = sd[t] - x;
}

__global__ void k_scanB(const int* __restrict__ degi, const int* __restrict__ boff,
                        int* __restrict__ cursor) {
  __shared__ int sd[256];
  int b = blockIdx.x, t = threadIdx.x;
  int v = b * 256 + t;
  int x = (v < N_NODES) ? degi[v] : 0;
  sd[t] = x;
  __syncthreads();
#pragma unroll
  for (int o = 1; o < 256; o <<= 1) {
    int val = (t >= o) ? sd[t - o] : 0;
    __syncthreads();
    sd[t] += val;
    __syncthreads();
  }
  if (v < N_NODES) cursor[v] = boff[b] + sd[t] - x;
}

__global__ void k_fill(const int* __restrict__ dst, int* __restrict__ cursor,
                       int* __restrict__ eperm) {
  int e = blockIdx.x * 256 + threadIdx.x;
  if (e < N_EDGES) {
    int pos = atomicAdd(&cursor[dst[e]], 1);
    eperm[pos] = e;
  }
}

// ================= prep2: permuted edge MLP (8 edges/block) + src/dst =================
static constexpr int S2_MLP = E_PAD / 8;   // 6272 blocks, 8 edges x 128 j
static constexpr int S2_SP  = 196;

__global__ void k_prep2(const BF* __restrict__ ea, const int* __restrict__ src,
                        const int* __restrict__ dst, const int* __restrict__ eperm,
                        const BF* __restrict__ w1, const BF* __restrict__ b1,
                        _Float16* __restrict__ hidf, int* __restrict__ spadp,
                        int* __restrict__ dpadp) {
  int bid = blockIdx.x, t = threadIdx.x;
  if (bid < S2_MLP) {
    __shared__ float eas[40];
    __shared__ int el8[8];
    if (t < 8) { int pos = bid * 8 + t; el8[t] = (pos < N_EDGES) ? eperm[pos] : -1; }
    __syncthreads();
    if (t < 40) { int e = el8[t / 5]; eas[t] = (e >= 0) ? ldf(ea, e * 5 + (t % 5)) : 0.f; }
    __syncthreads();
#pragma unroll
    for (int rep = 0; rep < 4; ++rep) {
      int item = t + rep * 256;
      int le = item >> 7, j = item & 127;
      int pos = bid * 8 + le;
      float v = 0.f;
      if (pos < N_EDGES) {
        float acc = ldf(b1, j);
#pragma unroll
        for (int i = 0; i < 5; ++i) acc += eas[le * 5 + i] * ldf(w1, j * 5 + i);
        v = fmaxf(acc, 0.f);
      }
      hidf[(size_t)pos * 128 + j] = (_Float16)v;
    }
    return;
  }
  bid -= S2_MLP;
  {
    int pos = bid * 256 + t;
    if (pos < E_PAD) {
      int e = (pos < N_EDGES) ? eperm[pos] : -1;
      spadp[pos] = (e >= 0) ? src[e] : 0;
      dpadp[pos] = (e >= 0) ? dst[e] : 0;
    }
  }
}

// ================= NNConv message kernel (r14 champion, verbatim) =================
// mt=2: 128 edges/block -> grid (392,2) = 784 blocks x 4 waves, 3 blocks/CU.
// LDS 34 KB: s 18 KB + 2x8 KB B double-buffer.
__launch_bounds__(256, 4)
__global__ void k_msg(const _Float16* __restrict__ h16, const _Float16* __restrict__ hidf,
                      const _Float16* __restrict__ Qs, const _Float16* __restrict__ b2s,
                      const int* __restrict__ spadp, const int* __restrict__ dpadp,
                      float* __restrict__ agg) {
  __shared__ _Float16 s_lds[128 * SROW];   // 18 KB
  __shared__ _Float16 b_lds[2][4096];      // 2 x 8 KB
  const int tid = threadIdx.x;
  const int wv = tid >> 6, ln = tid & 63;
  const int m0 = ln & 15, quad = ln >> 4;
  const int tb = blockIdx.x * 128;
  const int oh = blockIdx.y;

  // stage s: 2 thr/edge, 32 halves each
  {
    int el = tid >> 1, half = (tid & 1) * 32;
    int sp_ = spadp[tb + el];
    const uint4* hp4 = (const uint4*)(h16 + (size_t)sp_ * 64 + half);
#pragma unroll
    for (int c = 0; c < 4; ++c) *(uint4*)&s_lds[el * SROW + half + c * 8] = hp4[c];
  }
  // hid fragments: 2 m-tiles x 4 k-chunks (full K=128)
  h8 hvv[2][4];
#pragma unroll
  for (int mt = 0; mt < 2; ++mt) {
    int e = tb + wv * 32 + mt * 16 + m0;
    const _Float16* hp = hidf + (size_t)e * 128 + quad * 8;
#pragma unroll
    for (int c = 0; c < 4; ++c) hvv[mt][c] = *(const h8*)(hp + c * 32);
  }
  // prefetch dl=0 B tile (8 KB contiguous)
  uint4 breg[2];
  {
    const uint4* qb = (const uint4*)(Qs + (size_t)(oh * 64) * 4096);
    breg[0] = qb[tid];
    breg[1] = qb[tid + 256];
    *(uint4*)&b_lds[0][tid * 8] = breg[0];
    *(uint4*)&b_lds[0][(tid + 256) * 8] = breg[1];
  }
  __syncthreads();

  f4 acc[2][2];
#pragma unroll
  for (int mt = 0; mt < 2; ++mt)
#pragma unroll
    for (int ct = 0; ct < 2; ++ct)
#pragma unroll
      for (int j = 0; j < 4; ++j) acc[mt][ct][j] = 0.f;

  for (int dl = 0; dl < 64; ++dl) {
    int cur = dl & 1;
    if (dl < 63) {
      const uint4* qb = (const uint4*)(Qs + (size_t)(oh * 64 + dl + 1) * 4096);
      breg[0] = qb[tid];
      breg[1] = qb[tid + 256];
    }
    _Float16 sv[2];
#pragma unroll
    for (int mt = 0; mt < 2; ++mt)
      sv[mt] = s_lds[(wv * 32 + mt * 16 + m0) * SROW + dl];
#pragma unroll
    for (int tk = 0; tk < 4; ++tk) {
      h8 a[2];
#pragma unroll
      for (int mt = 0; mt < 2; ++mt) a[mt] = hvv[mt][tk] * sv[mt];
#pragma unroll
      for (int ctl = 0; ctl < 2; ++ctl) {
        h8 b = *(const h8*)&b_lds[cur][(tk * 2 + ctl) * 512 + ln * 8];
#pragma unroll
        for (int mt = 0; mt < 2; ++mt)
          acc[mt][ctl] = __builtin_amdgcn_mfma_f32_16x16x32_f16(a[mt], b, acc[mt][ctl], 0, 0, 0);
      }
    }
    if (dl < 63) {
      *(uint4*)&b_lds[cur ^ 1][tid * 8] = breg[0];
      *(uint4*)&b_lds[cur ^ 1][(tid + 256) * 8] = breg[1];
    }
    __syncthreads();
  }
  // b2 term: 2 extra K-steps, A = s rows (d-halves), B = b2 frags from L2
#pragma unroll
  for (int tp = 0; tp < 2; ++tp) {
    h8 a[2];
#pragma unroll
    for (int mt = 0; mt < 2; ++mt)
      a[mt] = *(const h8*)&s_lds[(wv * 32 + mt * 16 + m0) * SROW + tp * 32 + quad * 8];
#pragma unroll
    for (int ctl = 0; ctl < 2; ++ctl) {
      int sf = (tp << 2) | (oh * 2 + ctl);
      h8 b = *(const h8*)(b2s + sf * 512 + ln * 8);
#pragma unroll
      for (int mt = 0; mt < 2; ++mt)
        acc[mt][ctl] = __builtin_amdgcn_mfma_f32_16x16x32_f16(a[mt], b, acc[mt][ctl], 0, 0, 0);
    }
  }
  // epilogue: coalesced atomicAdd into this o-half's disjoint segment
#pragma unroll
  for (int mt = 0; mt < 2; ++mt) {
#pragma unroll
    for (int r = 0; r < 4; ++r) {
      int pos = tb + wv * 32 + mt * 16 + quad * 4 + r;
      if (pos < N_EDGES) {
        float* ap = agg + (size_t)dpadp[pos] * 64 + oh * 32 + m0;
        atomicAdd(ap, acc[mt][0][r]);
        atomicAdd(ap + 16, acc[mt][1][r]);
      }
    }
  }
}

// ================= fused m-build + GRU v2: 32-row blocks, 625 blocks =================
// Row split (race-free: each block owns its rows' agg/h). Wave w: rows
// (w>>1)*16, col-quarter cq=w&1 covering all 4 gates of its 32 o-values
// (ct = g*4 + cq*2 + cc) -> gates stay in-register, no LDS exchange.
__launch_bounds__(256, 2)
__global__ void k_gru(float* __restrict__ agg, const int* __restrict__ degi,
                      const BF* __restrict__ convb, const _Float16* __restrict__ W,
                      const float* __restrict__ bcat, float* __restrict__ h,
                      _Float16* __restrict__ h16) {
  __shared__ _Float16 xa[32 * BROW];    // 8.5 KB
  __shared__ _Float16 wb[256 * BROW];   // 68 KB
  __shared__ float bsh[256];
  int tid = threadIdx.x;
  int wv = tid >> 6, ln = tid & 63, m0 = ln & 15, quad = ln >> 4;
  int rowblk = blockIdx.x * 32;
  int rw = (wv >> 1) * 16;   // wave's row offset (0 or 16)
  int cq = wv & 1;           // col-quarter selector
  bsh[tid] = bcat[tid];
  // xa staging + inline agg re-zero (this block's rows only)
  {
    int r = tid >> 3, c0 = (tid & 7) * 16;
    int node = rowblk + r;
    _Float16 v[16];
    if (node < N_NODES) {
      if (c0 < 64) {  // m-part
        float inv = 1.f / (float)max(degi[node], 1);
        float* ap = agg + (size_t)node * 64 + c0;
#pragma unroll
        for (int i = 0; i < 16; i += 4) {
          float4 a = *(float4*)(ap + i);
          *(float4*)(ap + i) = make_float4(0.f, 0.f, 0.f, 0.f);
          v[i + 0] = (_Float16)fmaxf(a.x * inv + ldf(convb, c0 + i + 0), 0.f);
          v[i + 1] = (_Float16)fmaxf(a.y * inv + ldf(convb, c0 + i + 1), 0.f);
          v[i + 2] = (_Float16)fmaxf(a.z * inv + ldf(convb, c0 + i + 2), 0.f);
          v[i + 3] = (_Float16)fmaxf(a.w * inv + ldf(convb, c0 + i + 3), 0.f);
        }
      } else {        // h-part
        const float* hp = h + (size_t)node * 64 + (c0 - 64);
#pragma unroll
        for (int i = 0; i < 16; i += 4) {
          float4 hf = *(const float4*)(hp + i);
          v[i + 0] = (_Float16)hf.x; v[i + 1] = (_Float16)hf.y;
          v[i + 2] = (_Float16)hf.z; v[i + 3] = (_Float16)hf.w;
        }
      }
    } else {
#pragma unroll
      for (int i = 0; i < 16; ++i) v[i] = (_Float16)0.f;
    }
    *(uint4*)&xa[r * BROW + c0] = *(const uint4*)&v[0];
    *(uint4*)&xa[r * BROW + c0 + 8] = *(const uint4*)&v[8];
  }
#pragma unroll
  for (int c = 0; c < 16; ++c) {
    int i = tid + c * 256, r = i >> 4, ch = i & 15;
    *(uint4*)&wb[r * BROW + ch * 8] = *(const uint4*)(W + (size_t)r * 128 + ch * 8);
  }
  __syncthreads();
  f4 acc[8];
#pragma unroll
  for (int k = 0; k < 8; ++k)
#pragma unroll
    for (int j = 0; j < 4; ++j) acc[k][j] = 0.f;
#pragma unroll
  for (int t = 0; t < 4; ++t) {
    h8 a = *(const h8*)&xa[(rw + m0) * BROW + t * 32 + quad * 8];
#pragma unroll
    for (int g = 0; g < 4; ++g) {
#pragma unroll
      for (int cc = 0; cc < 2; ++cc) {
        int ct = g * 4 + cq * 2 + cc;
        h8 b = *(const h8*)&wb[(ct * 16 + m0) * BROW + t * 32 + quad * 8];
        acc[g * 2 + cc] = __builtin_amdgcn_mfma_f32_16x16x32_f16(a, b, acc[g * 2 + cc], 0, 0, 0);
      }
    }
  }
#pragma unroll
  for (int cc = 0; cc < 2; ++cc) {
    int o = (cq * 2 + cc) * 16 + m0;
    float br = bsh[o], bz = bsh[64 + o], bn = bsh[128 + o], bh2 = bsh[192 + o];
#pragma unroll
    for (int r = 0; r < 4; ++r) {
      int row = rowblk + rw + quad * 4 + r;
      if (row < N_NODES) {
        float rr = sigf(acc[cc][r] + br);
        float zz = sigf(acc[2 + cc][r] + bz);
        float nn = tanh_f(acc[4 + cc][r] + bn + rr * (acc[6 + cc][r] + bh2));
        size_t hi = (size_t)row * 64 + o;
        float hp = h[hi];
        float hn = (1.f - zz) * nn + zz * hp;
        h[hi] = hn;
        h16[hi] = (_Float16)hn;
      }
    }
  }
}

// ================= fused Set2Set (r10-verified) =================
__launch_bounds__(1024)
__global__ void k_s2s(const float* __restrict__ h, const int* __restrict__ seg,
                      const BF* __restrict__ wih, const BF* __restrict__ whh,
                      const BF* __restrict__ bih, const BF* __restrict__ bhh,
                      float* __restrict__ outp) {
  __shared__ float xrow[128], g[256], qrow[64], hc[64], ccs[64], rr_[64];
  __shared__ float evals[MAXSEG];
  __shared__ float wred[16], wred2[16], rpart[16 * 64];
  int b = blockIdx.x, t = threadIdx.x;
  int wv = t >> 6, ln = t & 63;   // 16 waves
  if (t < 64) { hc[t] = 0.f; ccs[t] = 0.f; rr_[t] = 0.f; }
  __syncthreads();
  int start = seg[b], end = seg[b + 1];
  int cnt = end - start;
  for (int st = 0; st < 3; ++st) {
    if (t < 64) xrow[t] = hc[t];
    else if (t < 128) xrow[t] = rr_[t - 64];
    __syncthreads();
    if (t < 256) {
      float acc = ldf(bih, t) + ldf(bhh, t);
      const float4* wr4 = (const float4*)(wih + t * 128);
#pragma unroll
      for (int i = 0; i < 32; ++i) {
        float4 wv4 = wr4[i];
        acc += xrow[i * 4] * wv4.x + xrow[i * 4 + 1] * wv4.y +
               xrow[i * 4 + 2] * wv4.z + xrow[i * 4 + 3] * wv4.w;
      }
      const float4* wr2 = (const float4*)(whh + t * 64);
#pragma unroll
      for (int i = 0; i < 16; ++i) {
        float4 wv4 = wr2[i];
        acc += xrow[i * 4] * wv4.x + xrow[i * 4 + 1] * wv4.y +
               xrow[i * 4 + 2] * wv4.z + xrow[i * 4 + 3] * wv4.w;
      }
      g[t] = acc;
    }
    __syncthreads();
    if (t < 64) {
      float ig = sigf(g[t]), fg = sigf(g[64 + t]);
      float gg = tanh_f(g[128 + t]), og = sigf(g[192 + t]);
      float c = fg * ccs[t] + ig * gg;
      ccs[t] = c;
      float hn = og * tanh_f(c);
      hc[t] = hn;
      qrow[t] = hn;
    }
    __syncthreads();
    float q = qrow[ln];
    float mw = -3.4e38f;
    for (int n0 = start + wv * 2; n0 < end; n0 += 32) {
      int n1 = n0 + 1;
      float p0 = h[(size_t)n0 * 64 + ln] * q;
      float p1 = (n1 < end) ? h[(size_t)n1 * 64 + ln] * q : 0.f;
#pragma unroll
      for (int off = 32; off > 0; off >>= 1) {
        p0 += __shfl_xor(p0, off);
        p1 += __shfl_xor(p1, off);
      }
      if (ln == 0) {
        evals[n0 - start] = p0;
        mw = fmaxf(mw, p0);
        if (n1 < end) { evals[n1 - start] = p1; mw = fmaxf(mw, p1); }
      }
    }
    if (ln == 0) wred[wv] = mw;
    __syncthreads();
    float gmax = -3.4e38f;
#pragma unroll
    for (int i = 0; i < 16; ++i) gmax = fmaxf(gmax, wred[i]);
    __syncthreads();
    float psum = 0.f;
    for (int i = t; i < cnt; i += 1024) {
      float a = __expf(evals[i] - gmax);
      evals[i] = a;
      psum += a;
    }
#pragma unroll
    for (int off = 32; off > 0; off >>= 1) psum += __shfl_xor(psum, off);
    if (ln == 0) wred2[wv] = psum;
    __syncthreads();
    float tsum = 0.f;
#pragma unroll
    for (int i = 0; i < 16; ++i) tsum += wred2[i];
    float inv = 1.f / fmaxf(tsum, 1e-30f);
    float racc = 0.f;
    for (int n0 = start + wv * 2; n0 < end; n0 += 32) {
      int n1 = n0 + 1;
      float a0 = evals[n0 - start] * h[(size_t)n0 * 64 + ln];
      float a1 = (n1 < end) ? evals[n1 - start] * h[(size_t)n1 * 64 + ln] : 0.f;
      racc += a0 + a1;
    }
    rpart[wv * 64 + ln] = racc;
    __syncthreads();
    if (t < 64) {
      float s = 0.f;
#pragma unroll
      for (int i = 0; i < 16; ++i) s += rpart[i * 64 + t];
      rr_[t] = s * inv;
    }
    __syncthreads();
  }
  if (t < 128) outp[b * 128 + t] = (t < 64) ? hc[t] : rr_[t - 64];
}

// ================= launch =================
extern "C" void kernel_launch(void* const* d_in, const int* in_sizes, int n_in,
                              void* d_out, int out_size, void* d_ws, size_t ws_size,
                              hipStream_t stream) {
  const BF* x      = (const BF*)d_in[0];
  const int* ei    = (const int*)d_in[1];
  const BF* ea     = (const BF*)d_in[2];
  const int* batch = (const int*)d_in[3];
  const BF* w0     = (const BF*)d_in[4];
  const BF* b0     = (const BF*)d_in[5];
  const BF* w1     = (const BF*)d_in[6];
  const BF* b1     = (const BF*)d_in[7];
  const BF* w2     = (const BF*)d_in[8];
  const BF* b2     = (const BF*)d_in[9];
  const BF* convb  = (const BF*)d_in[10];
  const BF* gwih   = (const BF*)d_in[11];
  const BF* gwhh   = (const BF*)d_in[12];
  const BF* gbih   = (const BF*)d_in[13];
  const BF* gbhh   = (const BF*)d_in[14];
  const BF* lwih   = (const BF*)d_in[15];
  const BF* lwhh   = (const BF*)d_in[16];
  const BF* lbih   = (const BF*)d_in[17];
  const BF* lbhh   = (const BF*)d_in[18];
  const int* src = ei;
  const int* dstp = ei + N_EDGES;

  char* w = (char*)d_ws;
  size_t off_b = 0;
  auto take = [&](size_t bytes) -> void* {
    void* p = w + off_b;
    off_b = (off_b + bytes + 255) & ~(size_t)255;
    return p;
  };
  _Float16* Qs   = (_Float16*)take((size_t)4096 * 128 * 2);
  _Float16* hidf = (_Float16*)take((size_t)E_PAD * 128 * 2);
  float* h       = (float*)take((size_t)N_NODES * 64 * 4);
  _Float16* h16  = (_Float16*)take((size_t)N_NODES * 64 * 2);
  float* zr      = (float*)take((size_t)(N_NODES * 64 + N_NODES + 128) * 4);  // agg|degi|bsum
  float* agg     = zr;
  int*   degi    = (int*)(zr + N_NODES * 64);
  int*   bsum    = degi + N_NODES;
  _Float16* Wcat = (_Float16*)take((size_t)256 * 128 * 2);
  float* bcat    = (float*)take((size_t)256 * 4);
  _Float16* b2s  = (_Float16*)take((size_t)8 * 512 * 2);
  int*   seg     = (int*)take((size_t)129 * 4);
  int*   boff    = (int*)take((size_t)128 * 4);
  int*   cursor  = (int*)take((size_t)N_NODES * 4);
  int*   eperm   = (int*)take((size_t)N_EDGES * 4);
  int*   spadp   = (int*)take((size_t)E_PAD * 4);
  int*   dpadp   = (int*)take((size_t)E_PAD * 4);

  hipMemsetAsync(zr, 0, (size_t)(N_NODES * 64 + N_NODES + 128) * 4, stream);
  k_prep1<<<PREP1_BLOCKS, 256, 0, stream>>>(x, batch, dstp, w0, b0, w2, b2,
                                            gwih, gwhh, gbih, gbhh,
                                            h, h16, Qs, Wcat, bcat, b2s,
                                            seg, degi, bsum);
  k_scanA<<<1, 128, 0, stream>>>(bsum, boff);
  k_scanB<<<N_B, 256, 0, stream>>>(degi, boff, cursor);
  k_fill<<<196, 256, 0, stream>>>(dstp, cursor, eperm);
  k_prep2<<<S2_MLP + S2_SP, 256, 0, stream>>>(ea, src, dstp, eperm, w1, b1,
                                              hidf, spadp, dpadp);
  for (int it = 0; it < 3; ++it) {
    k_msg<<<dim3(N_MSGB, 2), 256, 0, stream>>>(h16, hidf, Qs, b2s, spadp, dpadp, agg);
    k_gru<<<N_GRUB, 256, 0, stream>>>(agg, degi, convb, Wcat, bcat, h, h16);
  }
  k_s2s<<<128, 1024, 0, stream>>>(h, seg, lwih, lwhh, lbih, lbhh, (float*)d_out);
}